// Round 8
// baseline (135.444 us; speedup 1.0000x reference)
//
#include <hip/hip_runtime.h>
#include <hip/hip_bf16.h>

// Sizes (fixed by the problem)
#define VOCAB 50257
#define EMB   1024
#define HID   1024
#define OUTV  50257

// All float tensors are float32 on device (confirmed round 2).
//
// Model (R7): decoder streams at ~6.2-6.3 TB/s = the READ-path ceiling
// (m13: 6.29 TB/s); the 7 TB/s harness fills are write-side. Floor:
// 239.5MB/6.3 ~= 38us + ramp ~1 + launch ~1 = ~40us. R3/R7 two-kernel =
// 42.3us; the only addressable slack is the 2nd launch boundary (~1.6-2us,
// calibrated from R2->R3).
//
// R5 retro: fused spin barrier was CORRECT but tight-polling 1024 blocks
// collapsed the coherence point (~1e5 agent-reads/us on one line -> 180us).
// This round: same fused schedule, polls spaced by s_sleep(32) (~0.85us,
// ~100x fewer reads), phase B = contiguous 12-13-row chunk per wave.
// Failsafe poll cap -> wrong answer, never hang. If this lands >=42us the
// boundary is already minimal -> R7 kernel is the roofline.

__device__ __forceinline__ float wave_reduce(float v) {
    #pragma unroll
    for (int off = 32; off > 0; off >>= 1) v += __shfl_xor(v, off);
    return v;
}

__device__ __forceinline__ float dot4(float4 a, float4 b) {
    return a.x * b.x + a.y * b.y + a.z * b.z + a.w * b.w;
}

__global__ __launch_bounds__(256, 4) void k_milstm_fused(
        const int* __restrict__ inp,
        const float* __restrict__ emb,
        const float* __restrict__ Wx, const float* __restrict__ bx,
        const float* __restrict__ Wh, const float* __restrict__ bh,
        const float* __restrict__ h0,
        const float* __restrict__ alpha, const float* __restrict__ beta1,
        const float* __restrict__ beta2,
        const float* __restrict__ c0,
        const float* __restrict__ Wdec, const float* __restrict__ bdec,
        float* __restrict__ out,
        float* __restrict__ hx_ws,
        unsigned* __restrict__ bar) {
    __shared__ float m_s[4];

    const int g    = threadIdx.x >> 6;              // wave in block: gate 0..3
    const int lane = threadIdx.x & 63;
    const int j    = blockIdx.x;                    // hidden unit (grid == 1024)
    const int r    = g * HID + j;                   // gate row in [0,4096)

    // ---- Phase A: gates + cell (block j owns hidden unit j) ----
    {
        const size_t x_off = (size_t)inp[0] * (size_t)EMB;
        const float* wx_row = Wx + (size_t)r * EMB;
        const float* wh_row = Wh + (size_t)r * HID;

        float accx = 0.f, acch = 0.f;
        #pragma unroll
        for (int s = 0; s < 4; ++s) {
            const int c = s * 256 + lane * 4;       // 4 floats (16B) per lane
            float4 wxv = *(const float4*)(wx_row + c);
            float4 xv  = *(const float4*)(emb + x_off + c);
            float4 whv = *(const float4*)(wh_row + c);
            float4 hv  = *(const float4*)(h0 + c);
            accx += dot4(wxv, xv);
            acch += dot4(whv, hv);
        }
        accx = wave_reduce(accx);
        acch = wave_reduce(acch);

        if (lane == 0) {
            float gx = accx + bx[r];
            float gh = acch + bh[r];
            m_s[g] = alpha[r] * gx * gh + beta1[r] * gx + beta2[r] * gh;
        }
        __syncthreads();

        if (threadIdx.x == 0) {
            float fg = 1.f / (1.f + expf(-m_s[0]));
            float ig = 1.f / (1.f + expf(-m_s[1]));
            float og = 1.f / (1.f + expf(-m_s[2]));
            float zt = tanhf(m_s[3]);
            float c  = fg * c0[j] + ig * zt;
            float h  = og * tanhf(c);
            hx_ws[j]            = h;                // for phase B
            out[OUTV + j]       = h;                // hx output
            out[OUTV + HID + j] = c;                // cx output
        }
    }

    // ---- Grid handoff: sleep-spaced polling (R5 fix) ----
    if (threadIdx.x == 0) {
        __threadfence();                            // release hx_ws write
        atomicAdd(bar, 1u);                         // device-scope arrival
        unsigned polls = 0;
        while (__hip_atomic_load(bar, __ATOMIC_RELAXED,
                                 __HIP_MEMORY_SCOPE_AGENT) < 1024u) {
            __builtin_amdgcn_s_sleep(32);           // ~0.85us between polls
            if (++polls > 200000u) break;           // failsafe: fail, don't hang
        }
        __threadfence();                            // acquire remote hx_ws
    }
    __syncthreads();

    // ---- Phase B: decoder, contiguous 12-13-row chunk per wave ----
    // 4096 waves; waves < 1105 get 13 rows, rest 12 (covers 50257 exactly).
    const int c0c = lane * 4;
    float4 x0 = *(const float4*)(hx_ws + c0c);
    float4 x1 = *(const float4*)(hx_ws + 256 + c0c);
    float4 x2 = *(const float4*)(hx_ws + 512 + c0c);
    float4 x3 = *(const float4*)(hx_ws + 768 + c0c);

    const int w     = blockIdx.x * 4 + g;           // 0..4095
    int row         = w * 12 + (w < 1105 ? w : 1105);
    const int end   = row + 12 + (w < 1105 ? 1 : 0);

    for (; row + 1 < end; row += 2) {               // adjacent pairs
        const float* wA = Wdec + (size_t)row * HID;
        const float* wB = wA + HID;
        float4 a0 = *(const float4*)(wA + c0c);
        float4 a1 = *(const float4*)(wA + 256 + c0c);
        float4 a2 = *(const float4*)(wA + 512 + c0c);
        float4 a3 = *(const float4*)(wA + 768 + c0c);
        float4 b0 = *(const float4*)(wB + c0c);
        float4 b1 = *(const float4*)(wB + 256 + c0c);
        float4 b2 = *(const float4*)(wB + 512 + c0c);
        float4 b3 = *(const float4*)(wB + 768 + c0c);
        float accA = dot4(a0, x0) + dot4(a1, x1) + dot4(a2, x2) + dot4(a3, x3);
        float accB = dot4(b0, x0) + dot4(b1, x1) + dot4(b2, x2) + dot4(b3, x3);
        accA = wave_reduce(accA);
        accB = wave_reduce(accB);
        if (lane == 0) {
            out[row]     = accA + bdec[row];
            out[row + 1] = accB + bdec[row + 1];
        }
    }
    if (row < end) {                                 // odd tail row
        const float* wA = Wdec + (size_t)row * HID;
        float4 a0 = *(const float4*)(wA + c0c);
        float4 a1 = *(const float4*)(wA + 256 + c0c);
        float4 a2 = *(const float4*)(wA + 512 + c0c);
        float4 a3 = *(const float4*)(wA + 768 + c0c);
        float accA = dot4(a0, x0) + dot4(a1, x1) + dot4(a2, x2) + dot4(a3, x3);
        accA = wave_reduce(accA);
        if (lane == 0) out[row] = accA + bdec[row];
    }
}

extern "C" void kernel_launch(void* const* d_in, const int* in_sizes, int n_in,
                              void* d_out, int out_size, void* d_ws, size_t ws_size,
                              hipStream_t stream) {
    const int*   inp   = (const int*)d_in[0];
    const float* h0    = (const float*)d_in[1];
    const float* c0    = (const float*)d_in[2];
    const float* emb   = (const float*)d_in[3];
    const float* Wx    = (const float*)d_in[4];
    const float* bx    = (const float*)d_in[5];
    const float* Wh    = (const float*)d_in[6];
    const float* bh    = (const float*)d_in[7];
    const float* alpha = (const float*)d_in[8];
    const float* beta1 = (const float*)d_in[9];
    const float* beta2 = (const float*)d_in[10];
    const float* Wdec  = (const float*)d_in[11];
    const float* bdec  = (const float*)d_in[12];

    float* out      = (float*)d_out;           // [0,50257): out, then hx[1024], cx[1024]
    float*    hx_ws = (float*)d_ws;            // 1024 f32
    unsigned* bar   = (unsigned*)((char*)d_ws + 4096);

    hipMemsetAsync(bar, 0, sizeof(unsigned), stream);

    k_milstm_fused<<<1024, 256, 0, stream>>>(inp, emb, Wx, bx, Wh, bh, h0,
                                             alpha, beta1, beta2, c0,
                                             Wdec, bdec, out, hx_ws, bar);
}

// Round 9
// 50.972 us; speedup vs baseline: 2.6572x; 2.6572x over previous
//
#include <hip/hip_runtime.h>
#include <hip/hip_bf16.h>

// Sizes (fixed by the problem)
#define VOCAB 50257
#define EMB   1024
#define HID   1024
#define OUTV  50257

// All float tensors are float32 on device (confirmed round 2).
//
// History: R3/R7 two-kernel = 42.3us (decoder ~33us = 6.2 TB/s effective).
// R5 fused + tight spin = 180us; R8 fused + s_sleep-spaced polls = 195us/disp
// with FETCH 118MB @ 0.6 TB/s, VALUBusy 1.8% -> slowdown is POLL-RATE-
// INDEPENDENT; device-scope atomic+fence handoff degrades subsequent
// streaming ~10x. FUSION RETIRED (upside was ~2us, cost ~150us).
// Replays: ~118MB of 240MB comes from HBM, rest L3 (FETCH evidence).
//
// This round: MLP experiment. Decoder wave handles 4 ADJACENT rows (16KB
// chunk, 16 outstanding float4 loads vs R7's 8) to test whether the 6.2TB/s
// plateau is a per-wave outstanding-request limit (L3-hit stream should then
// overlap the HBM stream and lift effective BW above the pure-HBM ceiling).
// If neutral: 6.3TB/s is a true path ceiling -> R7/R9 kernel is roofline.

__device__ __forceinline__ float wave_reduce(float v) {
    #pragma unroll
    for (int off = 32; off > 0; off >>= 1) v += __shfl_xor(v, off);
    return v;
}

__device__ __forceinline__ float dot4(float4 a, float4 b) {
    return a.x * b.x + a.y * b.y + a.z * b.z + a.w * b.w;
}

// Kernel 1 (gates + cell): block j = hidden unit j (1024 blocks).
// Wave g computes gate row r = g*HID + j; thread 0 finishes the cell math.
__global__ __launch_bounds__(256) void k_gates_cell(
        const int* __restrict__ inp,
        const float* __restrict__ emb,
        const float* __restrict__ Wx, const float* __restrict__ bx,
        const float* __restrict__ Wh, const float* __restrict__ bh,
        const float* __restrict__ h0,
        const float* __restrict__ alpha, const float* __restrict__ beta1,
        const float* __restrict__ beta2,
        const float* __restrict__ c0,
        float* __restrict__ hx_ws,
        float* __restrict__ out_hx, float* __restrict__ out_cx) {
    __shared__ float m_s[4];

    const int g    = threadIdx.x >> 6;              // gate 0..3 (f,i,o,z)
    const int lane = threadIdx.x & 63;
    const int j    = blockIdx.x;                    // hidden unit
    const int r    = g * HID + j;                   // gate row in [0,4096)

    const size_t x_off = (size_t)inp[0] * (size_t)EMB;
    const float* wx_row = Wx + (size_t)r * EMB;
    const float* wh_row = Wh + (size_t)r * HID;

    float accx = 0.f, acch = 0.f;
    #pragma unroll
    for (int s = 0; s < 4; ++s) {
        const int c = s * 256 + lane * 4;           // 4 floats (16B) per lane
        float4 wxv = *(const float4*)(wx_row + c);
        float4 xv  = *(const float4*)(emb + x_off + c);
        float4 whv = *(const float4*)(wh_row + c);
        float4 hv  = *(const float4*)(h0 + c);
        accx += dot4(wxv, xv);
        acch += dot4(whv, hv);
    }
    accx = wave_reduce(accx);
    acch = wave_reduce(acch);

    if (lane == 0) {
        float gx = accx + bx[r];
        float gh = acch + bh[r];
        m_s[g] = alpha[r] * gx * gh + beta1[r] * gx + beta2[r] * gh;
    }
    __syncthreads();

    if (threadIdx.x == 0) {
        float fg = 1.f / (1.f + expf(-m_s[0]));
        float ig = 1.f / (1.f + expf(-m_s[1]));
        float og = 1.f / (1.f + expf(-m_s[2]));
        float zt = tanhf(m_s[3]);
        float c  = fg * c0[j] + ig * zt;
        float h  = og * tanhf(c);
        hx_ws[j]  = h;
        out_hx[j] = h;
        out_cx[j] = c;
    }
}

// Kernel 2: decoder. Wave g of block b handles 4 ADJACENT rows starting at
// 16b+4g (16 outstanding float4 loads). Per-lane hx slice in registers;
// no LDS, no syncthreads.
__global__ __launch_bounds__(256) void k_dec(
        const float* __restrict__ hx_ws,
        const float* __restrict__ Wdec, const float* __restrict__ bdec,
        float* __restrict__ out) {
    const int g    = threadIdx.x >> 6;
    const int lane = threadIdx.x & 63;
    const int c0   = lane * 4;

    // per-lane hx slice: columns c0 + {0,256,512,768} (+0..3). L1-hit.
    float4 x0 = *(const float4*)(hx_ws + c0);
    float4 x1 = *(const float4*)(hx_ws + 256 + c0);
    float4 x2 = *(const float4*)(hx_ws + 512 + c0);
    float4 x3 = *(const float4*)(hx_ws + 768 + c0);

    const int rowBase = blockIdx.x * 16 + g * 4;
    if (rowBase >= OUTV) return;

    if (rowBase + 4 <= OUTV) {
        const float* w0 = Wdec + (size_t)rowBase * HID;
        const float* w1 = w0 + HID;
        const float* w2 = w0 + 2 * HID;
        const float* w3 = w0 + 3 * HID;
        // 16 independent 16B loads in flight
        float4 a0 = *(const float4*)(w0 + c0);
        float4 a1 = *(const float4*)(w0 + 256 + c0);
        float4 a2 = *(const float4*)(w0 + 512 + c0);
        float4 a3 = *(const float4*)(w0 + 768 + c0);
        float4 b0 = *(const float4*)(w1 + c0);
        float4 b1 = *(const float4*)(w1 + 256 + c0);
        float4 b2 = *(const float4*)(w1 + 512 + c0);
        float4 b3 = *(const float4*)(w1 + 768 + c0);
        float4 d0 = *(const float4*)(w2 + c0);
        float4 d1 = *(const float4*)(w2 + 256 + c0);
        float4 d2 = *(const float4*)(w2 + 512 + c0);
        float4 d3 = *(const float4*)(w2 + 768 + c0);
        float4 e0 = *(const float4*)(w3 + c0);
        float4 e1 = *(const float4*)(w3 + 256 + c0);
        float4 e2 = *(const float4*)(w3 + 512 + c0);
        float4 e3 = *(const float4*)(w3 + 768 + c0);

        float acc0 = dot4(a0, x0) + dot4(a1, x1) + dot4(a2, x2) + dot4(a3, x3);
        float acc1 = dot4(b0, x0) + dot4(b1, x1) + dot4(b2, x2) + dot4(b3, x3);
        float acc2 = dot4(d0, x0) + dot4(d1, x1) + dot4(d2, x2) + dot4(d3, x3);
        float acc3 = dot4(e0, x0) + dot4(e1, x1) + dot4(e2, x2) + dot4(e3, x3);
        acc0 = wave_reduce(acc0);
        acc1 = wave_reduce(acc1);
        acc2 = wave_reduce(acc2);
        acc3 = wave_reduce(acc3);
        if (lane == 0) {
            out[rowBase]     = acc0 + bdec[rowBase];
            out[rowBase + 1] = acc1 + bdec[rowBase + 1];
            out[rowBase + 2] = acc2 + bdec[rowBase + 2];
            out[rowBase + 3] = acc3 + bdec[rowBase + 3];
        }
    } else {
        for (int row = rowBase; row < OUTV; ++row) {
            const float* wr = Wdec + (size_t)row * HID;
            float4 a0 = *(const float4*)(wr + c0);
            float4 a1 = *(const float4*)(wr + 256 + c0);
            float4 a2 = *(const float4*)(wr + 512 + c0);
            float4 a3 = *(const float4*)(wr + 768 + c0);
            float acc = dot4(a0, x0) + dot4(a1, x1) + dot4(a2, x2) + dot4(a3, x3);
            acc = wave_reduce(acc);
            if (lane == 0) out[row] = acc + bdec[row];
        }
    }
}

extern "C" void kernel_launch(void* const* d_in, const int* in_sizes, int n_in,
                              void* d_out, int out_size, void* d_ws, size_t ws_size,
                              hipStream_t stream) {
    const int*   inp   = (const int*)d_in[0];
    const float* h0    = (const float*)d_in[1];
    const float* c0    = (const float*)d_in[2];
    const float* emb   = (const float*)d_in[3];
    const float* Wx    = (const float*)d_in[4];
    const float* bx    = (const float*)d_in[5];
    const float* Wh    = (const float*)d_in[6];
    const float* bh    = (const float*)d_in[7];
    const float* alpha = (const float*)d_in[8];
    const float* beta1 = (const float*)d_in[9];
    const float* beta2 = (const float*)d_in[10];
    const float* Wdec  = (const float*)d_in[11];
    const float* bdec  = (const float*)d_in[12];

    float* out   = (float*)d_out;              // [0,50257): out, then hx[1024], cx[1024]
    float* hx_ws = (float*)d_ws;               // 1024 f32

    k_gates_cell<<<1024, 256, 0, stream>>>(inp, emb, Wx, bx, Wh, bh, h0,
                                           alpha, beta1, beta2, c0,
                                           hx_ws, out + OUTV, out + OUTV + HID);
    k_dec<<<(OUTV + 15) / 16, 256, 0, stream>>>(hx_ws, Wdec, bdec, out);
}

// Round 10
// 41.996 us; speedup vs baseline: 3.2252x; 1.2137x over previous
//
#include <hip/hip_runtime.h>
#include <hip/hip_bf16.h>

// Sizes (fixed by the problem)
#define VOCAB 50257
#define EMB   1024
#define HID   1024
#define OUTV  50257

// All float tensors are float32 on device (confirmed round 2).
//
// FINAL MODEL (R9): total bytes 239.5MB (Wdec 206 + Wx/Wh 33.5) at the
// measured READ-path ceiling 6.29 TB/s (m13) = 38.1us floor; + 2 launches
// + gates tail + ramp ~= 41-42us. This kernel (R7 structure) = 42.3us.
// Ledger of refuted alternatives:
//  - fusion w/ device-scope handoff: 135-195us (R5 tight-spin, R8 s_sleep
//    polls; slowdown poll-rate-INDEPENDENT -> handoff degrades streaming).
//  - persistent grid / distant row pairs: 45.7us (R6).
//  - 4 rows/wave MLP: 51.0us (R9; VGPR > 128 occupancy step halves
//    resident waves -> device MLP drops). Per-wave depth is NOT the
//    limiter; 6.3 TB/s is a true path ceiling.
// => This two-kernel structure is the roofline.

__device__ __forceinline__ float wave_reduce(float v) {
    #pragma unroll
    for (int off = 32; off > 0; off >>= 1) v += __shfl_xor(v, off);
    return v;
}

__device__ __forceinline__ float dot4(float4 a, float4 b) {
    return a.x * b.x + a.y * b.y + a.z * b.z + a.w * b.w;
}

// Kernel 1 (gates + cell): block j = hidden unit j (1024 blocks).
// Wave g computes gate row r = g*HID + j; thread 0 finishes the cell math.
__global__ __launch_bounds__(256) void k_gates_cell(
        const int* __restrict__ inp,
        const float* __restrict__ emb,
        const float* __restrict__ Wx, const float* __restrict__ bx,
        const float* __restrict__ Wh, const float* __restrict__ bh,
        const float* __restrict__ h0,
        const float* __restrict__ alpha, const float* __restrict__ beta1,
        const float* __restrict__ beta2,
        const float* __restrict__ c0,
        float* __restrict__ hx_ws,
        float* __restrict__ out_hx, float* __restrict__ out_cx) {
    __shared__ float m_s[4];

    const int g    = threadIdx.x >> 6;              // gate 0..3 (f,i,o,z)
    const int lane = threadIdx.x & 63;
    const int j    = blockIdx.x;                    // hidden unit
    const int r    = g * HID + j;                   // gate row in [0,4096)

    const size_t x_off = (size_t)inp[0] * (size_t)EMB;
    const float* wx_row = Wx + (size_t)r * EMB;
    const float* wh_row = Wh + (size_t)r * HID;

    float accx = 0.f, acch = 0.f;
    #pragma unroll
    for (int s = 0; s < 4; ++s) {
        const int c = s * 256 + lane * 4;           // 4 floats (16B) per lane
        float4 wxv = *(const float4*)(wx_row + c);
        float4 xv  = *(const float4*)(emb + x_off + c);
        float4 whv = *(const float4*)(wh_row + c);
        float4 hv  = *(const float4*)(h0 + c);
        accx += dot4(wxv, xv);
        acch += dot4(whv, hv);
    }
    accx = wave_reduce(accx);
    acch = wave_reduce(acch);

    if (lane == 0) {
        float gx = accx + bx[r];
        float gh = acch + bh[r];
        m_s[g] = alpha[r] * gx * gh + beta1[r] * gx + beta2[r] * gh;
    }
    __syncthreads();

    if (threadIdx.x == 0) {
        float fg = 1.f / (1.f + expf(-m_s[0]));
        float ig = 1.f / (1.f + expf(-m_s[1]));
        float og = 1.f / (1.f + expf(-m_s[2]));
        float zt = tanhf(m_s[3]);
        float c  = fg * c0[j] + ig * zt;
        float h  = og * tanhf(c);
        hx_ws[j]  = h;
        out_hx[j] = h;
        out_cx[j] = c;
    }
}

// Kernel 2: decoder. Block b covers rows [8b, 8b+8); wave g handles the
// ADJACENT pair rows 8b+2g, 8b+2g+1 (4KB apart -> one locality stream,
// 8 outstanding 16B loads). Per-lane hx slice in registers; no LDS, no sync.
__global__ __launch_bounds__(256) void k_dec(
        const float* __restrict__ hx_ws,
        const float* __restrict__ Wdec, const float* __restrict__ bdec,
        float* __restrict__ out) {
    const int g    = threadIdx.x >> 6;
    const int lane = threadIdx.x & 63;
    const int c0   = lane * 4;

    // per-lane hx slice: columns c0 + {0,256,512,768} (+0..3). L1-hit.
    float4 x0 = *(const float4*)(hx_ws + c0);
    float4 x1 = *(const float4*)(hx_ws + 256 + c0);
    float4 x2 = *(const float4*)(hx_ws + 512 + c0);
    float4 x3 = *(const float4*)(hx_ws + 768 + c0);

    const int rowA = blockIdx.x * 8 + g * 2;
    const int rowB = rowA + 1;
    if (rowA >= OUTV) return;

    const float* wA = Wdec + (size_t)rowA * HID;
    if (rowB < OUTV) {
        const float* wB = Wdec + (size_t)rowB * HID;
        float4 a0 = *(const float4*)(wA + c0);
        float4 a1 = *(const float4*)(wA + 256 + c0);
        float4 a2 = *(const float4*)(wA + 512 + c0);
        float4 a3 = *(const float4*)(wA + 768 + c0);
        float4 b0 = *(const float4*)(wB + c0);
        float4 b1 = *(const float4*)(wB + 256 + c0);
        float4 b2 = *(const float4*)(wB + 512 + c0);
        float4 b3 = *(const float4*)(wB + 768 + c0);
        float accA = dot4(a0, x0) + dot4(a1, x1) + dot4(a2, x2) + dot4(a3, x3);
        float accB = dot4(b0, x0) + dot4(b1, x1) + dot4(b2, x2) + dot4(b3, x3);
        accA = wave_reduce(accA);
        accB = wave_reduce(accB);
        if (lane == 0) {
            out[rowA] = accA + bdec[rowA];
            out[rowB] = accB + bdec[rowB];
        }
    } else {
        float4 a0 = *(const float4*)(wA + c0);
        float4 a1 = *(const float4*)(wA + 256 + c0);
        float4 a2 = *(const float4*)(wA + 512 + c0);
        float4 a3 = *(const float4*)(wA + 768 + c0);
        float accA = dot4(a0, x0) + dot4(a1, x1) + dot4(a2, x2) + dot4(a3, x3);
        accA = wave_reduce(accA);
        if (lane == 0) out[rowA] = accA + bdec[rowA];
    }
}

extern "C" void kernel_launch(void* const* d_in, const int* in_sizes, int n_in,
                              void* d_out, int out_size, void* d_ws, size_t ws_size,
                              hipStream_t stream) {
    const int*   inp   = (const int*)d_in[0];
    const float* h0    = (const float*)d_in[1];
    const float* c0    = (const float*)d_in[2];
    const float* emb   = (const float*)d_in[3];
    const float* Wx    = (const float*)d_in[4];
    const float* bx    = (const float*)d_in[5];
    const float* Wh    = (const float*)d_in[6];
    const float* bh    = (const float*)d_in[7];
    const float* alpha = (const float*)d_in[8];
    const float* beta1 = (const float*)d_in[9];
    const float* beta2 = (const float*)d_in[10];
    const float* Wdec  = (const float*)d_in[11];
    const float* bdec  = (const float*)d_in[12];

    float* out   = (float*)d_out;              // [0,50257): out, then hx[1024], cx[1024]
    float* hx_ws = (float*)d_ws;               // 1024 f32

    k_gates_cell<<<1024, 256, 0, stream>>>(inp, emb, Wx, bx, Wh, bh, h0,
                                           alpha, beta1, beta2, c0,
                                           hx_ws, out + OUTV, out + OUTV + HID);
    k_dec<<<(OUTV + 7) / 8, 256, 0, stream>>>(hx_ws, Wdec, bdec, out);
}